// Round 2
// baseline (153.416 us; speedup 1.0000x reference)
//
#include <hip/hip_runtime.h>
#include <math.h>

#define DIM 128
#define HEADS 8
#define HD 16
#define NPOS 8192      // 32*32*8
#define EPS 1e-5f

// ---- f16 helpers -------------------------------------------------
typedef _Float16 half2_t __attribute__((ext_vector_type(2)));

static __device__ __forceinline__ half2_t u2h(unsigned u) {
    half2_t r; __builtin_memcpy(&r, &u, 4); return r;
}
static __device__ __forceinline__ unsigned pkh(float a, float b) {
    half2_t h; h.x = (_Float16)a; h.y = (_Float16)b;
    unsigned u; __builtin_memcpy(&u, &h, 4); return u;
}
// dot of one f16 channel-pair against q channel-pair, fp32 accumulate
static __device__ __forceinline__ float dot2(unsigned k, unsigned q, float acc) {
#if __has_builtin(__builtin_amdgcn_fdot2)
    return __builtin_amdgcn_fdot2(u2h(k), u2h(q), acc, false);
#else
    half2_t kh = u2h(k), qh = u2h(q);
    acc = fmaf((float)kh.x, (float)qh.x, acc);
    return fmaf((float)kh.y, (float)qh.y, acc);
#endif
}

// ---------------- instance-norm stats ----------------
// ws: [0,128) mu_x [128,256) rs_x [256,384) mu_s [384,512) rs_s
__global__ __launch_bounds__(256) void stats_kernel(const float* __restrict__ x,
                                                    const float* __restrict__ skip,
                                                    float* __restrict__ ws) {
    int c = blockIdx.x;
    const float* src; int n; float* mu_out; float* rs_out; int ci;
    if (c < DIM) { ci = c; src = x + c * 1024; n = 1024; mu_out = ws; rs_out = ws + DIM; }
    else { ci = c - DIM; src = skip + (size_t)ci * NPOS; n = NPOS; mu_out = ws + 2*DIM; rs_out = ws + 3*DIM; }
    int t = threadIdx.x;
    const float4* s4 = (const float4*)src;
    int n4 = n >> 2;
    float s = 0.f, s2 = 0.f;
    for (int i = t; i < n4; i += 256) {
        float4 v = s4[i];
        s += (v.x + v.y) + (v.z + v.w);
        s2 = fmaf(v.x, v.x, fmaf(v.y, v.y, fmaf(v.z, v.z, fmaf(v.w, v.w, s2))));
    }
    #pragma unroll
    for (int off = 32; off > 0; off >>= 1) {
        s  += __shfl_down(s,  off, 64);
        s2 += __shfl_down(s2, off, 64);
    }
    __shared__ float ls[4], ls2[4];
    int wv = t >> 6;
    if ((t & 63) == 0) { ls[wv] = s; ls2[wv] = s2; }
    __syncthreads();
    if (t == 0) {
        float S  = ls[0] + ls[1] + ls[2] + ls[3];
        float S2 = ls2[0] + ls2[1] + ls2[2] + ls2[3];
        float inv_n = 1.f / (float)n;
        float mu  = S * inv_n;
        float var = S2 * inv_n - mu * mu;
        mu_out[ci] = mu;
        rs_out[ci] = rsqrtf(var + EPS);
    }
}

// ---------------- q/k/v projections: f16 LDS, 8x8 register tile ----------------
// Tile = 128 pos x 128 ch per block; A and W staged as f16 (32KB+32KB -> 2 blk/CU).
// Thread (pg=t&15, cg=t>>4) owns 8 pos x 8 ch: per ci just 2 ds_read_b128 for
// 128 FLOP (0.25 B/FLOP vs 1.0 before) -> LDS instr count / 4.
// which: 0=q (8 blocks, 1024 distinct rows since x is 2x-upsampled), 1=k, 2=v.
__global__ __launch_bounds__(256) void qkv_kernel(const float* __restrict__ x,
                                                  const float* __restrict__ skip,
                                                  const float* __restrict__ Wq, const float* __restrict__ bq,
                                                  const float* __restrict__ Wk, const float* __restrict__ bk,
                                                  const float* __restrict__ Wv, const float* __restrict__ bv,
                                                  const float* __restrict__ ws,
                                                  unsigned* __restrict__ q_out,
                                                  unsigned* __restrict__ k_out,
                                                  unsigned* __restrict__ v_out) {
    __shared__ __align__(16) _Float16 ah[128 * 128];   // [ci][pos]
    __shared__ __align__(16) _Float16 wh[128 * 128];   // [ci][co]
    int which = blockIdx.y;
    if (which == 0 && blockIdx.x >= 8) return;         // q: only 1024 rows
    int t = threadIdx.x;
    int n0 = blockIdx.x * 128;

    const float* W = (which == 0) ? Wq : (which == 1) ? Wk : Wv;
    const float* b = (which == 0) ? bq : (which == 1) ? bk : bv;
    const float* mu = (which == 0) ? ws : ws + 2*DIM;
    const float* rs = (which == 0) ? ws + DIM : ws + 3*DIM;

    {
        const float4* W4 = (const float4*)W;
        for (int i4 = t; i4 < 4096; i4 += 256) {
            int ci = i4 >> 5, j4 = i4 & 31;
            float4 w = W4[ci * 32 + j4];
            *(uint2*)&wh[ci * 128 + j4 * 4] = make_uint2(pkh(w.x, w.y), pkh(w.z, w.w));
        }
    }
    if (which == 0) {
        const float4* x4 = (const float4*)x;
        for (int i4 = t; i4 < 4096; i4 += 256) {
            int ci = i4 >> 5, j4 = i4 & 31;
            float4 f = x4[ci * 256 + (n0 >> 2) + j4];
            float m_ = mu[ci], r_ = rs[ci];
            *(uint2*)&ah[ci * 128 + j4 * 4] =
                make_uint2(pkh((f.x - m_) * r_, (f.y - m_) * r_),
                           pkh((f.z - m_) * r_, (f.w - m_) * r_));
        }
    } else {
        for (int i4 = t; i4 < 4096; i4 += 256) {
            int ci = i4 >> 5, j4 = i4 & 31;
            float4 f = *(const float4*)(skip + (size_t)ci * NPOS + n0 + j4 * 4);
            float m_ = mu[ci], r_ = rs[ci];
            *(uint2*)&ah[ci * 128 + j4 * 4] =
                make_uint2(pkh((f.x - m_) * r_, (f.y - m_) * r_),
                           pkh((f.z - m_) * r_, (f.w - m_) * r_));
        }
    }
    __syncthreads();

    int pg = t & 15, cg = t >> 4;
    float4 b0 = *(const float4*)(b + cg * 8);
    float4 b1 = *(const float4*)(b + cg * 8 + 4);
    float acc[8][8];
    #pragma unroll
    for (int p = 0; p < 8; ++p) {
        acc[p][0] = b0.x; acc[p][1] = b0.y; acc[p][2] = b0.z; acc[p][3] = b0.w;
        acc[p][4] = b1.x; acc[p][5] = b1.y; acc[p][6] = b1.z; acc[p][7] = b1.w;
    }

    const _Float16* ap = ah + pg * 8;
    const _Float16* wp = wh + cg * 8;
    #pragma unroll 4
    for (int ci = 0; ci < 128; ++ci) {
        uint4 au = *(const uint4*)(ap + ci * 128);
        uint4 wu = *(const uint4*)(wp + ci * 128);
        half2_t a0 = u2h(au.x), a1 = u2h(au.y), a2 = u2h(au.z), a3 = u2h(au.w);
        half2_t w0 = u2h(wu.x), w1 = u2h(wu.y), w2 = u2h(wu.z), w3 = u2h(wu.w);
        float af[8] = { (float)a0.x, (float)a0.y, (float)a1.x, (float)a1.y,
                        (float)a2.x, (float)a2.y, (float)a3.x, (float)a3.y };
        float wf[8] = { (float)w0.x, (float)w0.y, (float)w1.x, (float)w1.y,
                        (float)w2.x, (float)w2.y, (float)w3.x, (float)w3.y };
        #pragma unroll
        for (int p = 0; p < 8; ++p)
            #pragma unroll
            for (int c = 0; c < 8; ++c)
                acc[p][c] = fmaf(af[p], wf[c], acc[p][c]);
    }

    int p0 = n0 + pg * 8;
    if (which == 0) {
        #pragma unroll
        for (int p = 0; p < 8; ++p) {
            uint4 o;
            o.x = pkh(acc[p][0] * 0.25f, acc[p][1] * 0.25f);
            o.y = pkh(acc[p][2] * 0.25f, acc[p][3] * 0.25f);
            o.z = pkh(acc[p][4] * 0.25f, acc[p][5] * 0.25f);
            o.w = pkh(acc[p][6] * 0.25f, acc[p][7] * 0.25f);
            *(uint4*)(q_out + (size_t)(p0 + p) * 64 + cg * 4) = o;
        }
    } else {
        unsigned* outp = (which == 1) ? k_out : v_out;
        #pragma unroll
        for (int p = 0; p < 8; ++p) {
            uint4 o;
            o.x = pkh(acc[p][0], acc[p][1]);
            o.y = pkh(acc[p][2], acc[p][3]);
            o.z = pkh(acc[p][4], acc[p][5]);
            o.w = pkh(acc[p][6], acc[p][7]);
            *(uint4*)(outp + (size_t)(p0 + p) * 64 + cg * 4) = o;
        }
    }
}

// ---------------- neighborhood attention: z-pair sharing ----------------
// Key fact: q rows for z-pair (2m,2m+1) are IDENTICAL (x upsampled 2x) and
// the pair shares h/w windows. One thread owns a z-pair: one QK dot and one
// k/v LDS read serve both positions -> LDS b128 traffic per (pos,nbr) halves.
// Pair iterates the union z-window (5x5x6 = 150 pts; ~17% masked when the two
// z-windows coincide). grid 512 = 64 tiles(4x4 h,w) x 8 heads; 512 thr =
// 64 z-pairs x 8 slots. Halo 8x8x8; LDS ~37 KB -> 4 blocks/CU, no grid tail.
__global__ __launch_bounds__(512, 4) void attn_kernel(const unsigned* __restrict__ qb,
                                                      const unsigned* __restrict__ kb,
                                                      const unsigned* __restrict__ vb,
                                                      const float* __restrict__ rpb,
                                                      float* __restrict__ ao_t) {
    __shared__ uint4 kbf[2 * 544];   // 17408 B, slot = gh*68 + gw*8 + ((gz+gw)&7)
    __shared__ uint4 vbf[2 * 544];   // 17408 B
    __shared__ float bias_l[744];    // 729 + zero pad (masked lanes may index 729..743)

    int blk = blockIdx.x;
    int h    = blk & 7;
    int tile = blk >> 3;             // 0..63
    int h0 = (tile >> 3) * 4;
    int w0 = (tile & 7) * 4;
    int bh0 = min(max(h0 - 2, 0), 24);
    int bw0 = min(max(w0 - 2, 0), 24);
    int t = threadIdx.x;

    // ---- stage k/v halo: 512 nbrs x 2 chunk-halves, direct 16B copies ----
    for (int idx = t; idx < 1024; idx += 512) {
        int c2 = idx & 1;
        int r  = idx >> 1;               // 0..511
        int gz = r & 7;
        int q2 = r >> 3;                 // 0..63
        int gh = q2 >> 3, gw = q2 & 7;
        int n = (bh0 + gh) * 256 + (bw0 + gw) * 8 + gz;
        int base = gh * 68 + gw * 8 + ((gz + gw) & 7);
        kbf[c2 * 544 + base] = *(const uint4*)(kb + (size_t)n * 64 + h * 8 + c2 * 4);
        vbf[c2 * 544 + base] = *(const uint4*)(vb + (size_t)n * 64 + h * 8 + c2 * 4);
    }
    for (int idx = t; idx < 744; idx += 512) bias_l[idx] = (idx < 729) ? rpb[h * 729 + idx] : 0.f;
    __syncthreads();

    int s = t & 7, p = t >> 3;           // 8 slots x 64 z-pairs
    int ph = p >> 4, pw = (p >> 2) & 3, pzp = p & 3;
    int hc = h0 + ph, wc = w0 + pw, zc0 = pzp * 2;   // pair = (zc0, zc0+1)
    int sh = min(max(hc - 2, 0), 27);
    int sw = min(max(wc - 2, 0), 27);
    int sz0 = min(max(zc0 - 2, 0), 3);
    int sz1 = min(max(zc0 - 1, 0), 3);
    int dlt = sz1 - sz0;                 // 0 or 1: z-window shift of pos1 vs pos0
    int hb = sh - bh0, wb = sw - bw0;
    int b0 = (sh - hc + 4) * 81 + (sw - wc + 4) * 9 + (sz0 - zc0 + 4);
    // bias index for pos1 = b0 - 1 (zc1 = zc0+1, same zlo)
    int n0pos = hc * 256 + wc * 8 + zc0;

    // shared q (identical for both z's of the pair), f16-packed: 8 ch-pairs
    int qrow = (hc >> 1) * 64 + (wc >> 1) * 4 + pzp;
    uint4 qa = *(const uint4*)(qb + (size_t)qrow * 64 + h * 8);
    uint4 qc = *(const uint4*)(qb + (size_t)qrow * 64 + h * 8 + 4);

    float o0[16], o1[16];
    #pragma unroll
    for (int d = 0; d < 16; ++d) { o0[d] = 0.f; o1[d] = 0.f; }
    float l0 = 0.f, l1 = 0.f;

    // slot partition of the 150 union points: s<6 -> 19, else 18
    int cnt   = 18 + (s < 6);
    int start = s * 18 + min(s, 6);
    int i0 = p & 15;                     // stagger (15 < 18 always)

    for (int it = 0; it < cnt; ++it) {
        int ii = i0 + it; if (ii >= cnt) ii -= cnt;
        int j = start + ii;              // 0..149
        int jh = (j * 2185) >> 16;       // j / 30
        int jr = j - jh * 30;
        int jw = (jr * 43) >> 8;         // jr / 6
        int jz = jr - jw * 6;            // 0..5 (union z index)
        int gw = wb + jw;
        int gz = sz0 + jz;
        int base = (hb + jh) * 68 + gw * 8 + ((gz + gw) & 7);
        int joff = jh * 81 + jw * 9 + jz;
        float bias1 = bias_l[b0 + joff - 1];
        float bias0 = bias_l[b0 + joff];

        uint4 ka = kbf[base];
        uint4 k2 = kbf[544 + base];
        float d0 = dot2(ka.x, qa.x, 0.f);
        float d1 = dot2(ka.y, qa.y, 0.f);
        d0 = dot2(ka.z, qa.z, d0);
        d1 = dot2(ka.w, qa.w, d1);
        d0 = dot2(k2.x, qc.x, d0);
        d1 = dot2(k2.y, qc.y, d1);
        d0 = dot2(k2.z, qc.z, d0);
        d1 = dot2(k2.w, qc.w, d1);
        float d = d0 + d1;               // shared: q identical for the pair

        bool v0ok = (jz < 5);                         // pos0 window: [0,4]
        bool v1ok = ((unsigned)(jz - dlt) < 5u);      // pos1 window: [dlt, dlt+4]
        float e0 = __expf(d + bias0);
        float e1 = __expf(d + bias1);
        float pp0 = v0ok ? e0 : 0.f;
        float pp1 = v1ok ? e1 : 0.f;
        l0 += pp0; l1 += pp1;

        uint4 va = vbf[base];
        uint4 v2 = vbf[544 + base];
        #define PV(u, dd) { half2_t vh = u2h(u); float f0 = (float)vh.x, f1 = (float)vh.y; \
            o0[dd]   = fmaf(pp0, f0, o0[dd]);   o1[dd]   = fmaf(pp1, f0, o1[dd]); \
            o0[dd+1] = fmaf(pp0, f1, o0[dd+1]); o1[dd+1] = fmaf(pp1, f1, o1[dd+1]); }
        PV(va.x, 0)  PV(va.y, 2)  PV(va.z, 4)  PV(va.w, 6)
        PV(v2.x, 8)  PV(v2.y, 10) PV(v2.z, 12) PV(v2.w, 14)
        #undef PV
    }

    // merge 8 slots (adjacent lanes)
    #pragma unroll
    for (int step = 1; step <= 4; step <<= 1) {
        l0 += __shfl_xor(l0, step, 64);
        l1 += __shfl_xor(l1, step, 64);
        #pragma unroll
        for (int d = 0; d < 16; ++d) {
            o0[d] += __shfl_xor(o0[d], step, 64);
            o1[d] += __shfl_xor(o1[d], step, 64);
        }
    }
    float inv0 = 1.f / l0, inv1 = 1.f / l1;
    // lane s stores dims 2s, 2s+1 for both positions (cols n0pos, n0pos+1)
    int row = h * 16 + 2 * s;
    float2 r0 = make_float2(o0[2*s]     * inv0, o1[2*s]     * inv1);
    float2 r1 = make_float2(o0[2*s + 1] * inv0, o1[2*s + 1] * inv1);
    *(float2*)(ao_t + (size_t)row       * NPOS + n0pos) = r0;
    *(float2*)(ao_t + (size_t)(row + 1) * NPOS + n0pos) = r1;
}

// ---------------- output projection: f16 LDS, 8x8 register tile ----------------
__global__ __launch_bounds__(256) void proj_kernel(const float* __restrict__ ao_t,
                                                   const float* __restrict__ Wo,
                                                   const float* __restrict__ bo,
                                                   float* __restrict__ out) {
    __shared__ __align__(16) _Float16 ah[128 * 128];   // [ci][pos]
    __shared__ __align__(16) _Float16 wh[128 * 128];   // [ci][co]
    int t = threadIdx.x;
    int n0 = blockIdx.x * 128;

    {
        const float4* W4 = (const float4*)Wo;
        for (int i4 = t; i4 < 4096; i4 += 256) {
            int ci = i4 >> 5, j4 = i4 & 31;
            float4 w = W4[ci * 32 + j4];
            *(uint2*)&wh[ci * 128 + j4 * 4] = make_uint2(pkh(w.x, w.y), pkh(w.z, w.w));
        }
    }
    for (int i4 = t; i4 < 4096; i4 += 256) {
        int ci = i4 >> 5, j4 = i4 & 31;
        float4 f = *(const float4*)(ao_t + (size_t)ci * NPOS + n0 + j4 * 4);
        *(uint2*)&ah[ci * 128 + j4 * 4] = make_uint2(pkh(f.x, f.y), pkh(f.z, f.w));
    }
    __syncthreads();

    int pg = t & 15, cg = t >> 4;
    float4 b0 = *(const float4*)(bo + cg * 8);
    float4 b1 = *(const float4*)(bo + cg * 8 + 4);
    float acc[8][8];
    #pragma unroll
    for (int p = 0; p < 8; ++p) {
        acc[p][0] = b0.x; acc[p][1] = b0.y; acc[p][2] = b0.z; acc[p][3] = b0.w;
        acc[p][4] = b1.x; acc[p][5] = b1.y; acc[p][6] = b1.z; acc[p][7] = b1.w;
    }

    const _Float16* ap = ah + pg * 8;
    const _Float16* wp = wh + cg * 8;
    #pragma unroll 4
    for (int ci = 0; ci < 128; ++ci) {
        uint4 au = *(const uint4*)(ap + ci * 128);
        uint4 wu = *(const uint4*)(wp + ci * 128);
        half2_t a0 = u2h(au.x), a1 = u2h(au.y), a2 = u2h(au.z), a3 = u2h(au.w);
        half2_t w0 = u2h(wu.x), w1 = u2h(wu.y), w2 = u2h(wu.z), w3 = u2h(wu.w);
        float af[8] = { (float)a0.x, (float)a0.y, (float)a1.x, (float)a1.y,
                        (float)a2.x, (float)a2.y, (float)a3.x, (float)a3.y };
        float wf[8] = { (float)w0.x, (float)w0.y, (float)w1.x, (float)w1.y,
                        (float)w2.x, (float)w2.y, (float)w3.x, (float)w3.y };
        #pragma unroll
        for (int p = 0; p < 8; ++p)
            #pragma unroll
            for (int c = 0; c < 8; ++c)
                acc[p][c] = fmaf(af[p], wf[c], acc[p][c]);
    }

    int p0 = n0 + pg * 8;
    int co0 = cg * 8;
    #pragma unroll
    for (int c = 0; c < 8; ++c) {
        float* op = out + (size_t)(co0 + c) * NPOS + p0;
        *(float4*)op       = make_float4(acc[0][c], acc[1][c], acc[2][c], acc[3][c]);
        *(float4*)(op + 4) = make_float4(acc[4][c], acc[5][c], acc[6][c], acc[7][c]);
    }
}

extern "C" void kernel_launch(void* const* d_in, const int* in_sizes, int n_in,
                              void* d_out, int out_size, void* d_ws, size_t ws_size,
                              hipStream_t stream) {
    const float* x    = (const float*)d_in[0];
    const float* skip = (const float*)d_in[1];
    const float* Wq   = (const float*)d_in[2];
    const float* bq   = (const float*)d_in[3];
    const float* Wk   = (const float*)d_in[4];
    const float* bk   = (const float*)d_in[5];
    const float* Wv   = (const float*)d_in[6];
    const float* bv   = (const float*)d_in[7];
    const float* rpb  = (const float*)d_in[8];
    const float* Wo   = (const float*)d_in[9];
    const float* bo   = (const float*)d_in[10];
    float* out = (float*)d_out;

    float*    ws   = (float*)d_ws;
    unsigned* q    = (unsigned*)(ws + 512);              // 1024*64 uints (f16x2), 256 KB
    unsigned* kbp  = q + 1024 * 64;                      // 8192*64 uints packed f16
    unsigned* vbp  = kbp + (size_t)NPOS * 64;
    float*    ao_t = (float*)(vbp + (size_t)NPOS * 64);  // 8192*128 fp32

    stats_kernel<<<256, 256, 0, stream>>>(x, skip, ws);
    qkv_kernel<<<dim3(64, 3), 256, 0, stream>>>(x, skip, Wq, bq, Wk, bk, Wv, bv, ws, q, kbp, vbp);
    attn_kernel<<<512, 512, 0, stream>>>(q, kbp, vbp, rpb, ao_t);
    proj_kernel<<<64, 256, 0, stream>>>(ao_t, Wo, bo, out);
}

// Round 3
// 115.698 us; speedup vs baseline: 1.3260x; 1.3260x over previous
//
#include <hip/hip_runtime.h>
#include <math.h>

#define DIM 128
#define HEADS 8
#define HD 16
#define NPOS 8192      // 32*32*8
#define EPS 1e-5f

// ---- f16 helpers -------------------------------------------------
typedef _Float16 half2_t __attribute__((ext_vector_type(2)));
typedef _Float16 f16x8  __attribute__((ext_vector_type(8)));
typedef float    f32x4  __attribute__((ext_vector_type(4)));

static __device__ __forceinline__ half2_t u2h(unsigned u) {
    half2_t r; __builtin_memcpy(&r, &u, 4); return r;
}
static __device__ __forceinline__ unsigned pkh(float a, float b) {
    half2_t h; h.x = (_Float16)a; h.y = (_Float16)b;
    unsigned u; __builtin_memcpy(&u, &h, 4); return u;
}
// dot of one f16 channel-pair against q channel-pair, fp32 accumulate
static __device__ __forceinline__ float dot2(unsigned k, unsigned q, float acc) {
#if __has_builtin(__builtin_amdgcn_fdot2)
    return __builtin_amdgcn_fdot2(u2h(k), u2h(q), acc, false);
#else
    half2_t kh = u2h(k), qh = u2h(q);
    acc = fmaf((float)kh.x, (float)qh.x, acc);
    return fmaf((float)kh.y, (float)qh.y, acc);
#endif
}

// ---------------- instance-norm stats + W-transpose ----------------
// blocks 0..255: per-channel stats.  ws: [0,128) mu_x [128,256) rs_x
//                                        [256,384) mu_s [384,512) rs_s
// blocks 256..271: transpose the 4 weight matrices into Wt[co][ci] f16
// (16 blocks: 4 matrices x 4 ci-chunks of 32).
__global__ __launch_bounds__(256) void stats_kernel(const float* __restrict__ x,
                                                    const float* __restrict__ skip,
                                                    const float* __restrict__ Wq,
                                                    const float* __restrict__ Wk,
                                                    const float* __restrict__ Wv,
                                                    const float* __restrict__ Wo,
                                                    float* __restrict__ ws,
                                                    unsigned short* __restrict__ Wt) {
    int c = blockIdx.x;
    int t = threadIdx.x;
    if (c >= 256) {
        int c2 = c - 256;
        int m = c2 >> 2, chunk = c2 & 3;
        const float* Wsrc = (m == 0) ? Wq : (m == 1) ? Wk : (m == 2) ? Wv : Wo;
        unsigned short* dst = Wt + (size_t)m * 16384;
        int co = t & 127, half = t >> 7;
        int ci0 = chunk * 32 + half * 16;
        unsigned pk8[8];
        #pragma unroll
        for (int j = 0; j < 8; ++j) {
            float a = Wsrc[(ci0 + 2*j    ) * 128 + co];
            float b = Wsrc[(ci0 + 2*j + 1) * 128 + co];
            pk8[j] = pkh(a, b);
        }
        *(uint4*)(dst + (size_t)co * 128 + ci0)     = *(uint4*)&pk8[0];
        *(uint4*)(dst + (size_t)co * 128 + ci0 + 8) = *(uint4*)&pk8[4];
        return;
    }
    const float* src; int n; float* mu_out; float* rs_out; int ci;
    if (c < DIM) { ci = c; src = x + c * 1024; n = 1024; mu_out = ws; rs_out = ws + DIM; }
    else { ci = c - DIM; src = skip + (size_t)ci * NPOS; n = NPOS; mu_out = ws + 2*DIM; rs_out = ws + 3*DIM; }
    const float4* s4 = (const float4*)src;
    int n4 = n >> 2;
    float s = 0.f, s2 = 0.f;
    for (int i = t; i < n4; i += 256) {
        float4 v = s4[i];
        s += (v.x + v.y) + (v.z + v.w);
        s2 = fmaf(v.x, v.x, fmaf(v.y, v.y, fmaf(v.z, v.z, fmaf(v.w, v.w, s2))));
    }
    #pragma unroll
    for (int off = 32; off > 0; off >>= 1) {
        s  += __shfl_down(s,  off, 64);
        s2 += __shfl_down(s2, off, 64);
    }
    __shared__ float ls[4], ls2[4];
    int wv = t >> 6;
    if ((t & 63) == 0) { ls[wv] = s; ls2[wv] = s2; }
    __syncthreads();
    if (t == 0) {
        float S  = ls[0] + ls[1] + ls[2] + ls[3];
        float S2 = ls2[0] + ls2[1] + ls2[2] + ls2[3];
        float inv_n = 1.f / (float)n;
        float mu  = S * inv_n;
        float var = S2 * inv_n - mu * mu;
        mu_out[ci] = mu;
        rs_out[ci] = rsqrtf(var + EPS);
    }
}

// ---------------- unified MFMA GEMM: C = norm(A) @ W + b ----------------
// Block: 32 pos x 128 co, 256 thr = 4 waves; wave w owns co [w*32,w*32+32).
// A staged f16 [pos][ci] in LDS (8KB), XOR-swizzled ((pos&7)<<4).
// W frags read from pre-transposed Wt[co][ci] f16 directly into VGPRs.
// mfma_f32_16x16x32_f16: A-op = Wt rows (M=co), B-op = A rows (N=pos)
// -> D[co][pos]; lane holds 4 consecutive co at one pos -> uint2 f16-pair
// stores (phase 0: q/k/v packed) or 4 dword stores (phase 1: out[co][pos]).
// phase 0 grid: 0..255 k, 256..511 v, 512..543 q.  phase 1 grid: 256 (o).
__global__ __launch_bounds__(256) void gemm_kernel(int phase,
    const float* __restrict__ x, const float* __restrict__ skip,
    const float* __restrict__ ao_t,
    const unsigned short* __restrict__ Wt_all,
    const float* __restrict__ bq, const float* __restrict__ bk,
    const float* __restrict__ bv, const float* __restrict__ bo,
    const float* __restrict__ ws,
    unsigned* __restrict__ q_out, unsigned* __restrict__ k_out,
    unsigned* __restrict__ v_out, float* __restrict__ out) {
    __shared__ __align__(16) unsigned short A_lds[32 * 128];   // 8 KB
    int bx = blockIdx.x;
    const float* A; int lda; const float* mu; const float* rs;
    const unsigned short* Wt; const float* bias; float scale = 1.f;
    unsigned* opk = nullptr; float* of = nullptr; int n0;
    if (phase == 0) {
        if (bx < 256)      { A = skip; lda = NPOS; mu = ws + 256; rs = ws + 384;
                             Wt = Wt_all + 16384;     bias = bk; opk = k_out; n0 = bx * 32; }
        else if (bx < 512) { A = skip; lda = NPOS; mu = ws + 256; rs = ws + 384;
                             Wt = Wt_all + 2 * 16384; bias = bv; opk = v_out; n0 = (bx - 256) * 32; }
        else               { A = x;    lda = 1024; mu = ws;       rs = ws + 128;
                             Wt = Wt_all;             bias = bq; opk = q_out; n0 = (bx - 512) * 32;
                             scale = 0.25f; }
    } else {
        A = ao_t; lda = NPOS; mu = nullptr; rs = nullptr;
        Wt = Wt_all + 3 * 16384; bias = bo; of = out; n0 = bx * 32;
    }
    int t = threadIdx.x;
    int lane = t & 63, w = t >> 6;

    // ---- preload W fragments (global, L2-hot): mt(2) x k4(4) = 8 x b128
    int co_f = w * 32 + (lane & 15);
    int kf   = (lane >> 4) * 8;
    uint4 wf[2][4];
    #pragma unroll
    for (int mt = 0; mt < 2; ++mt)
        #pragma unroll
        for (int k4 = 0; k4 < 4; ++k4)
            wf[mt][k4] = *(const uint4*)(Wt + (size_t)(co_f + mt * 16) * 128 + k4 * 32 + kf);

    // ---- stage A -> LDS f16 [pos][ci] (swizzled); 4 ci per b64 write
    {
        int pos = t & 31, g = t >> 5;          // g 0..7
        const float* ap = A + n0 + pos;
        float f[16];
        #pragma unroll
        for (int rep = 0; rep < 4; ++rep) {
            int ci0 = g * 4 + rep * 32;
            f[rep*4+0] = ap[(size_t)(ci0    ) * lda];
            f[rep*4+1] = ap[(size_t)(ci0 + 1) * lda];
            f[rep*4+2] = ap[(size_t)(ci0 + 2) * lda];
            f[rep*4+3] = ap[(size_t)(ci0 + 3) * lda];
        }
        #pragma unroll
        for (int rep = 0; rep < 4; ++rep) {
            int ci0 = g * 4 + rep * 32;
            float f0 = f[rep*4+0], f1 = f[rep*4+1], f2 = f[rep*4+2], f3 = f[rep*4+3];
            if (phase == 0) {
                f0 = (f0 - mu[ci0    ]) * rs[ci0    ];
                f1 = (f1 - mu[ci0 + 1]) * rs[ci0 + 1];
                f2 = (f2 - mu[ci0 + 2]) * rs[ci0 + 2];
                f3 = (f3 - mu[ci0 + 3]) * rs[ci0 + 3];
            }
            int byte = (pos * 256 + ci0 * 2) ^ ((pos & 7) << 4);
            *(uint2*)((char*)A_lds + byte) = make_uint2(pkh(f0, f1), pkh(f2, f3));
        }
    }
    __syncthreads();

    // ---- MFMA: 2 m-tiles x 2 n-tiles x 4 k-steps
    f32x4 acc[2][2];
    #pragma unroll
    for (int mt = 0; mt < 2; ++mt)
        #pragma unroll
        for (int nt = 0; nt < 2; ++nt)
            acc[mt][nt] = (f32x4){0.f, 0.f, 0.f, 0.f};
    #pragma unroll
    for (int k4 = 0; k4 < 4; ++k4) {
        f16x8 af[2];
        #pragma unroll
        for (int nt = 0; nt < 2; ++nt) {
            int pos = nt * 16 + (lane & 15);
            int byte = (pos * 256 + (k4 * 32 + kf) * 2) ^ ((pos & 7) << 4);
            uint4 u = *(const uint4*)((const char*)A_lds + byte);
            __builtin_memcpy(&af[nt], &u, 16);
        }
        #pragma unroll
        for (int mt = 0; mt < 2; ++mt) {
            f16x8 wfr; __builtin_memcpy(&wfr, &wf[mt][k4], 16);
            acc[mt][0] = __builtin_amdgcn_mfma_f32_16x16x32_f16(wfr, af[0], acc[mt][0], 0, 0, 0);
            acc[mt][1] = __builtin_amdgcn_mfma_f32_16x16x32_f16(wfr, af[1], acc[mt][1], 0, 0, 0);
        }
    }

    // ---- epilogue: lane holds co = base + (lane>>4)*4 + r at pos = base + (lane&15)
    int colp  = lane & 15;
    int rquad = (lane >> 4) * 4;
    #pragma unroll
    for (int mt = 0; mt < 2; ++mt) {
        int co = w * 32 + mt * 16 + rquad;
        float4 bv4 = *(const float4*)(bias + co);
        #pragma unroll
        for (int nt = 0; nt < 2; ++nt) {
            int pos = n0 + nt * 16 + colp;
            float v0 = (acc[mt][nt][0] + bv4.x) * scale;
            float v1 = (acc[mt][nt][1] + bv4.y) * scale;
            float v2 = (acc[mt][nt][2] + bv4.z) * scale;
            float v3 = (acc[mt][nt][3] + bv4.w) * scale;
            if (phase == 0) {
                *(uint2*)(opk + (size_t)pos * 64 + (co >> 1)) = make_uint2(pkh(v0, v1), pkh(v2, v3));
            } else {
                of[(size_t)(co    ) * NPOS + pos] = v0;
                of[(size_t)(co + 1) * NPOS + pos] = v1;
                of[(size_t)(co + 2) * NPOS + pos] = v2;
                of[(size_t)(co + 3) * NPOS + pos] = v3;
            }
        }
    }
}

// ---------------- neighborhood attention: z-pair sharing ----------------
// q rows for z-pair (2m,2m+1) are IDENTICAL (x upsampled 2x); one thread owns
// a z-pair: one QK dot and one k/v LDS read serve both positions. Pair
// iterates the union z-window (5x5x6 = 150 pts). grid 512 = 64 tiles x 8
// heads; 512 thr = 64 z-pairs x 8 slots. Halo 8x8x8; LDS ~37 KB.
__global__ __launch_bounds__(512, 4) void attn_kernel(const unsigned* __restrict__ qb,
                                                      const unsigned* __restrict__ kb,
                                                      const unsigned* __restrict__ vb,
                                                      const float* __restrict__ rpb,
                                                      float* __restrict__ ao_t) {
    __shared__ uint4 kbf[2 * 544];   // slot = gh*68 + gw*8 + ((gz+gw)&7)
    __shared__ uint4 vbf[2 * 544];
    __shared__ float bias_l[744];

    int blk = blockIdx.x;
    int h    = blk & 7;
    int tile = blk >> 3;
    int h0 = (tile >> 3) * 4;
    int w0 = (tile & 7) * 4;
    int bh0 = min(max(h0 - 2, 0), 24);
    int bw0 = min(max(w0 - 2, 0), 24);
    int t = threadIdx.x;

    for (int idx = t; idx < 1024; idx += 512) {
        int c2 = idx & 1;
        int r  = idx >> 1;
        int gz = r & 7;
        int q2 = r >> 3;
        int gh = q2 >> 3, gw = q2 & 7;
        int n = (bh0 + gh) * 256 + (bw0 + gw) * 8 + gz;
        int base = gh * 68 + gw * 8 + ((gz + gw) & 7);
        kbf[c2 * 544 + base] = *(const uint4*)(kb + (size_t)n * 64 + h * 8 + c2 * 4);
        vbf[c2 * 544 + base] = *(const uint4*)(vb + (size_t)n * 64 + h * 8 + c2 * 4);
    }
    for (int idx = t; idx < 744; idx += 512) bias_l[idx] = (idx < 729) ? rpb[h * 729 + idx] : 0.f;
    __syncthreads();

    int s = t & 7, p = t >> 3;
    int ph = p >> 4, pw = (p >> 2) & 3, pzp = p & 3;
    int hc = h0 + ph, wc = w0 + pw, zc0 = pzp * 2;
    int sh = min(max(hc - 2, 0), 27);
    int sw = min(max(wc - 2, 0), 27);
    int sz0 = min(max(zc0 - 2, 0), 3);
    int sz1 = min(max(zc0 - 1, 0), 3);
    int dlt = sz1 - sz0;
    int hb = sh - bh0, wb = sw - bw0;
    int b0 = (sh - hc + 4) * 81 + (sw - wc + 4) * 9 + (sz0 - zc0 + 4);
    int n0pos = hc * 256 + wc * 8 + zc0;

    int qrow = (hc >> 1) * 64 + (wc >> 1) * 4 + pzp;
    uint4 qa = *(const uint4*)(qb + (size_t)qrow * 64 + h * 8);
    uint4 qc = *(const uint4*)(qb + (size_t)qrow * 64 + h * 8 + 4);

    float o0[16], o1[16];
    #pragma unroll
    for (int d = 0; d < 16; ++d) { o0[d] = 0.f; o1[d] = 0.f; }
    float l0 = 0.f, l1 = 0.f;

    int cnt   = 18 + (s < 6);
    int start = s * 18 + min(s, 6);
    int i0 = p & 15;

    for (int it = 0; it < cnt; ++it) {
        int ii = i0 + it; if (ii >= cnt) ii -= cnt;
        int j = start + ii;
        int jh = (j * 2185) >> 16;
        int jr = j - jh * 30;
        int jw = (jr * 43) >> 8;
        int jz = jr - jw * 6;
        int gw = wb + jw;
        int gz = sz0 + jz;
        int base = (hb + jh) * 68 + gw * 8 + ((gz + gw) & 7);
        int joff = jh * 81 + jw * 9 + jz;
        float bias1 = bias_l[b0 + joff - 1];
        float bias0 = bias_l[b0 + joff];

        uint4 ka = kbf[base];
        uint4 k2 = kbf[544 + base];
        float d0 = dot2(ka.x, qa.x, 0.f);
        float d1 = dot2(ka.y, qa.y, 0.f);
        d0 = dot2(ka.z, qa.z, d0);
        d1 = dot2(ka.w, qa.w, d1);
        d0 = dot2(k2.x, qc.x, d0);
        d1 = dot2(k2.y, qc.y, d1);
        d0 = dot2(k2.z, qc.z, d0);
        d1 = dot2(k2.w, qc.w, d1);
        float d = d0 + d1;

        bool v0ok = (jz < 5);
        bool v1ok = ((unsigned)(jz - dlt) < 5u);
        float e0 = __expf(d + bias0);
        float e1 = __expf(d + bias1);
        float pp0 = v0ok ? e0 : 0.f;
        float pp1 = v1ok ? e1 : 0.f;
        l0 += pp0; l1 += pp1;

        uint4 va = vbf[base];
        uint4 v2 = vbf[544 + base];
        #define PV(u, dd) { half2_t vh = u2h(u); float f0 = (float)vh.x, f1 = (float)vh.y; \
            o0[dd]   = fmaf(pp0, f0, o0[dd]);   o1[dd]   = fmaf(pp1, f0, o1[dd]); \
            o0[dd+1] = fmaf(pp0, f1, o0[dd+1]); o1[dd+1] = fmaf(pp1, f1, o1[dd+1]); }
        PV(va.x, 0)  PV(va.y, 2)  PV(va.z, 4)  PV(va.w, 6)
        PV(v2.x, 8)  PV(v2.y, 10) PV(v2.z, 12) PV(v2.w, 14)
        #undef PV
    }

    #pragma unroll
    for (int step = 1; step <= 4; step <<= 1) {
        l0 += __shfl_xor(l0, step, 64);
        l1 += __shfl_xor(l1, step, 64);
        #pragma unroll
        for (int d = 0; d < 16; ++d) {
            o0[d] += __shfl_xor(o0[d], step, 64);
            o1[d] += __shfl_xor(o1[d], step, 64);
        }
    }
    float inv0 = 1.f / l0, inv1 = 1.f / l1;
    int row = h * 16 + 2 * s;
    float2 r0 = make_float2(o0[2*s]     * inv0, o1[2*s]     * inv1);
    float2 r1 = make_float2(o0[2*s + 1] * inv0, o1[2*s + 1] * inv1);
    *(float2*)(ao_t + (size_t)row       * NPOS + n0pos) = r0;
    *(float2*)(ao_t + (size_t)(row + 1) * NPOS + n0pos) = r1;
}

extern "C" void kernel_launch(void* const* d_in, const int* in_sizes, int n_in,
                              void* d_out, int out_size, void* d_ws, size_t ws_size,
                              hipStream_t stream) {
    const float* x    = (const float*)d_in[0];
    const float* skip = (const float*)d_in[1];
    const float* Wq   = (const float*)d_in[2];
    const float* bq   = (const float*)d_in[3];
    const float* Wk   = (const float*)d_in[4];
    const float* bk   = (const float*)d_in[5];
    const float* Wv   = (const float*)d_in[6];
    const float* bv   = (const float*)d_in[7];
    const float* rpb  = (const float*)d_in[8];
    const float* Wo   = (const float*)d_in[9];
    const float* bo   = (const float*)d_in[10];
    float* out = (float*)d_out;

    float*          ws  = (float*)d_ws;
    unsigned short* Wt  = (unsigned short*)(ws + 512);      // 4*16384 f16 = 128 KB
    unsigned* q   = (unsigned*)(Wt + 4 * 16384);            // 1024*64 uints (f16x2)
    unsigned* kbp = q + 1024 * 64;                          // 8192*64 packed f16
    unsigned* vbp = kbp + (size_t)NPOS * 64;
    float*    ao_t = (float*)(vbp + (size_t)NPOS * 64);     // 8192*128 fp32

    stats_kernel<<<272, 256, 0, stream>>>(x, skip, Wq, Wk, Wv, Wo, ws, Wt);
    gemm_kernel<<<544, 256, 0, stream>>>(0, x, skip, ao_t, Wt, bq, bk, bv, bo, ws,
                                         q, kbp, vbp, out);
    attn_kernel<<<512, 512, 0, stream>>>(q, kbp, vbp, rpb, ao_t);
    gemm_kernel<<<256, 256, 0, stream>>>(1, x, skip, ao_t, Wt, bq, bk, bv, bo, ws,
                                         q, kbp, vbp, out);
}